// Round 4
// baseline (223.075 us; speedup 1.0000x reference)
//
#include <hip/hip_runtime.h>
#include <hip/hip_bf16.h>

// Problem constants (fixed by setup_inputs)
#define BQ_TOTAL 4800          // B*NQ = 16*300
#define D_MODEL 256
#define N_HEADS 8
#define SUM_POINTS 16
#define HEAD_DIM 32
#define SEQ 8500
#define OUT_ELEMS (BQ_TOTAL * D_MODEL)      // 1228800
#define NPTS_TOTAL (BQ_TOTAL * N_HEADS * SUM_POINTS)   // 614400

typedef _Float16 half8 __attribute__((ext_vector_type(8)));
typedef _Float16 half4 __attribute__((ext_vector_type(4)));
typedef float floatx4 __attribute__((ext_vector_type(4)));

// ---------------- Kernel 1: logits GEMM via f16 MFMA (unchanged) ----------------
#define LDK 264   // 256 + 8 f16 pad -> 528 B row stride

__global__ __launch_bounds__(256) void gemm_logits_mfma(
    const float* __restrict__ hs,
    const float* __restrict__ w_off, const float* __restrict__ b_off,
    const float* __restrict__ w_attn, const float* __restrict__ b_attn,
    float* __restrict__ off_out, float* __restrict__ attn_out)
{
    __shared__ _Float16 Asld[64 * LDK];
    __shared__ _Float16 Bsld[64 * LDK];

    const int tid = threadIdx.x;
    const int row0 = blockIdx.x * 64;       // query rows
    const int col0 = blockIdx.y * 64;       // output cols in [0,384)

    const float* Bsrc; const float* bias;
    if (col0 < 256) { Bsrc = w_off  + (size_t)col0 * 256;        bias = b_off  + col0; }
    else            { Bsrc = w_attn + (size_t)(col0 - 256) * 256; bias = b_attn + (col0 - 256); }

    // --- stage A and B tiles (64 x 256 each), fp32 -> f16 convert ---
    #pragma unroll
    for (int i = 0; i < 16; i++) {
        const int idx = tid + i * 256;      // 0..4095
        const int r = idx >> 6;             // 0..63
        const int kc = (idx & 63) << 2;     // 0..252, step 4

        const float4 a = *(const float4*)(hs + (size_t)(row0 + r) * 256 + kc);
        half4 ah; ah[0] = (_Float16)a.x; ah[1] = (_Float16)a.y;
                  ah[2] = (_Float16)a.z; ah[3] = (_Float16)a.w;
        *(half4*)&Asld[r * LDK + kc] = ah;

        const float4 b = *(const float4*)(Bsrc + (size_t)r * 256 + kc);
        half4 bh; bh[0] = (_Float16)b.x; bh[1] = (_Float16)b.y;
                  bh[2] = (_Float16)b.z; bh[3] = (_Float16)b.w;
        *(half4*)&Bsld[r * LDK + kc] = bh;
    }
    __syncthreads();

    // --- MFMA compute: A-frag m=lane&15 (row), k=quad*8+j; B-frag n=lane&15 (col) ---
    const int wv = tid >> 6;
    const int lane = tid & 63;
    const int m = lane & 15;
    const int quad = lane >> 4;

    half8 af[8];
    #pragma unroll
    for (int q8 = 0; q8 < 8; q8++)
        af[q8] = *(const half8*)&Asld[(wv * 16 + m) * LDK + q8 * 32 + quad * 8];

    floatx4 acc[4] = {{0.f,0.f,0.f,0.f},{0.f,0.f,0.f,0.f},{0.f,0.f,0.f,0.f},{0.f,0.f,0.f,0.f}};
    #pragma unroll
    for (int ct = 0; ct < 4; ct++) {
        #pragma unroll
        for (int q8 = 0; q8 < 8; q8++) {
            const half8 bf = *(const half8*)&Bsld[(ct * 16 + m) * LDK + q8 * 32 + quad * 8];
            acc[ct] = __builtin_amdgcn_mfma_f32_16x16x32_f16(af[q8], bf, acc[ct], 0, 0, 0);
        }
    }

    // --- epilogue: C/D layout col=lane&15, row=quad*4+reg; bias in fp32 ---
    #pragma unroll
    for (int ct = 0; ct < 4; ct++) {
        const int col_l = ct * 16 + m;        // 0..63 within tile
        const float bv = bias[col_l];
        #pragma unroll
        for (int rg = 0; rg < 4; rg++) {
            const int row = row0 + wv * 16 + quad * 4 + rg;
            const float v = acc[ct][rg] + bv;
            if (col0 < 256)
                off_out[(size_t)row * 256 + col0 + col_l] = v;
            else
                attn_out[(size_t)row * 128 + (col0 - 256) + col_l] = v;
        }
    }
}

// ---------------- Kernel 2 (NEW): per-point prep ----------------
// One lane per (bq,h,p). Does ONCE what deform_sample used to do 4x per
// point (softmax, location math, bilinear weights), with prob folded
// into the corner weights. Writes {int4 idx, float4 w} to workspace and
// probs to attn (the second output).
// Index identity: g = bq*128 + h*16 + p is exactly the attn flat index.
__global__ __launch_bounds__(256) void prep_points(
    const float* __restrict__ refp,     // (4800, 4)
    const float* __restrict__ offlog,   // ws (4800, 256)
    float* __restrict__ attn,           // (4800, 128): logits in -> probs out
    int4* __restrict__ idx_buf,         // (614400,) corner indices (in-batch)
    float4* __restrict__ w_buf)         // (614400,) corner weights * prob
{
    const int g = blockIdx.x * 256 + threadIdx.x;   // 0..614399
    const int p = g & 15;
    const int h = (g >> 4) & 7;
    const int bq = g >> 7;

    // loads (all coalesced; refp broadcast per bq)
    const float l = attn[g];
    const float2 off2 = *(const float2*)(offlog + (size_t)bq * 256 + h * 32 + 2 * p);
    const float4 rp4 = *(const float4*)(refp + (size_t)bq * 4);

    // softmax over the 16 points = lane bits 0..3 (strides 1,2,4,8)
    float m = l;
    #pragma unroll
    for (int s = 1; s < 16; s <<= 1) m = fmaxf(m, __shfl_xor(m, s));
    const float e = __expf(l - m);
    float ssum = e;
    #pragma unroll
    for (int s = 1; s < 16; s <<= 1) ssum += __shfl_xor(ssum, s);
    const float prob = e / ssum;
    attn[g] = prob;                     // second output

    // sampling location
    const int lvl = p >> 2;
    const int Wl = 80 >> lvl;           // square levels
    int base = 0;
    if (lvl == 1) base = 6400;
    else if (lvl == 2) base = 8000;
    else if (lvl == 3) base = 8400;

    const float Wf = (float)Wl;
    // offset = logit * (1/P=0.25) * ref_wh * OFFSET_SCALE(0.5) = logit * 0.125 * wh
    const float gx = (rp4.x + off2.x * 0.125f * rp4.z) * Wf - 0.5f;
    const float gy = (rp4.y + off2.y * 0.125f * rp4.w) * Wf - 0.5f;
    const float x0f = floorf(gx), y0f = floorf(gy);
    const float fx = gx - x0f, fy = gy - y0f;
    const int x0 = (int)x0f, y0 = (int)y0f;

    int   ii[4];
    float ww[4];
    #pragma unroll
    for (int c = 0; c < 4; c++) {
        const int xc = x0 + (c & 1);
        const int yc = y0 + (c >> 1);
        const float wx = (c & 1) ? fx : (1.0f - fx);
        const float wy = (c >> 1) ? fy : (1.0f - fy);
        const bool valid = (xc >= 0) && (xc < Wl) && (yc >= 0) && (yc < Wl);
        const int xi = min(max(xc, 0), Wl - 1);
        const int yi = min(max(yc, 0), Wl - 1);
        ii[c] = base + yi * Wl + xi;                    // always in [0, 8500)
        ww[c] = valid ? wx * wy * prob : 0.0f;          // prob folded in
    }
    int4 iv; iv.x = ii[0]; iv.y = ii[1]; iv.z = ii[2]; iv.w = ii[3];
    float4 wv; wv.x = ww[0]; wv.y = ww[1]; wv.z = ww[2]; wv.w = ww[3];
    idx_buf[g] = iv;
    w_buf[g] = wv;
}

// ---------------- Kernel 3: slim gather + weighted sum ----------------
// Pure gather + FMA + reduce. All scalar per-point math moved to prep.
__global__ __launch_bounds__(256) void deform_sample(
    const float* __restrict__ enc,      // (16, 8500, 256)
    const int4* __restrict__ idx_buf,
    const float4* __restrict__ w_buf,
    float* __restrict__ out)            // (4800, 256)
{
    const int tid = threadIdx.x;
    const int w = tid >> 6;
    const int lane = tid & 63;

    // XCD-chunked bijective swizzle (9600 % 8 == 0)
    const int orig = blockIdx.x;
    const int bswz = (orig & 7) * 1200 + (orig >> 3);

    const int item = bswz * 4 + w;         // 0..38399  (= bq*8 + h)
    const int bq = item >> 3;
    const int h = item & 7;
    const int p = lane >> 2;               // point 0..15
    const int sub = lane & 3;              // channel subgroup

    const int g = (item << 4) | p;         // = bq*128 + h*16 + p
    const int4 iv = idx_buf[g];            // broadcast across 4 sub lanes
    const float4 wv = w_buf[g];

    const int b = bq / 300;
    const float* pbase = enc + ((size_t)b * SEQ) * 256 + h * 32 + sub * 4;

    float vals[8] = {0.f,0.f,0.f,0.f,0.f,0.f,0.f,0.f};
    const int  idx4[4] = {iv.x, iv.y, iv.z, iv.w};
    const float wgt4[4] = {wv.x, wv.y, wv.z, wv.w};
    #pragma unroll
    for (int c = 0; c < 4; c++) {
        const float* vp = pbase + ((size_t)idx4[c] << 8);   // *256 channels
        const float4 va = *(const float4*)(vp);
        const float4 vb = *(const float4*)(vp + 16);
        const float wgt = wgt4[c];
        vals[0] += wgt * va.x; vals[1] += wgt * va.y;
        vals[2] += wgt * va.z; vals[3] += wgt * va.w;
        vals[4] += wgt * vb.x; vals[5] += wgt * vb.y;
        vals[6] += wgt * vb.z; vals[7] += wgt * vb.w;
    }

    // --- point reduction, 16 shuffles total ---
    // stage 1: s=32 half-exchange with role swap.
    float red[4];
    #pragma unroll
    for (int i = 0; i < 4; i++) {
        const float send = (lane & 32) ? vals[i] : vals[i + 4];
        const float recv = __shfl_xor(send, 32);
        red[i] = ((lane & 32) ? vals[i + 4] : vals[i]) + recv;
    }
    // stage 2: remaining point bits (lanes' bits 2..4)
    #pragma unroll
    for (int s = 4; s < 32; s <<= 1) {
        #pragma unroll
        for (int i = 0; i < 4; i++) red[i] += __shfl_xor(red[i], s);
    }

    // one representative per (half, sub): lanes 0..3 and 32..35
    if ((lane & 28) == 0) {
        float4 v; v.x = red[0]; v.y = red[1]; v.z = red[2]; v.w = red[3];
        *(float4*)(out + (size_t)bq * 256 + h * 32 + ((lane >> 5) << 4) + (sub << 2)) = v;
    }
}

extern "C" void kernel_launch(void* const* d_in, const int* in_sizes, int n_in,
                              void* d_out, int out_size, void* d_ws, size_t ws_size,
                              hipStream_t stream) {
    const float* hs     = (const float*)d_in[0];   // (16,300,256)
    const float* enc    = (const float*)d_in[1];   // (16,8500,256)
    const float* refp   = (const float*)d_in[2];   // (16,300,1,4)
    // d_in[3] = spatial_shapes (int64) — static, hardcoded
    const float* w_off  = (const float*)d_in[4];   // (256,256)
    const float* b_off  = (const float*)d_in[5];   // (256,)
    const float* w_attn = (const float*)d_in[6];   // (128,256)
    const float* b_attn = (const float*)d_in[7];   // (128,)

    float* out  = (float*)d_out;            // (16,300,256)
    float* attn = out + OUT_ELEMS;          // (16,300,8,16)

    // workspace layout
    float* offlog = (float*)d_ws;                       // 4800*256 f32 = 4.9 MB
    int4*  idx_buf = (int4*)((char*)d_ws + (size_t)BQ_TOTAL * 256 * 4);          // 9.8 MB
    float4* w_buf  = (float4*)((char*)idx_buf + (size_t)NPTS_TOTAL * 16);        // 9.8 MB

    dim3 g1(BQ_TOTAL / 64, 384 / 64);       // (75, 6)
    gemm_logits_mfma<<<g1, 256, 0, stream>>>(hs, w_off, b_off, w_attn, b_attn, offlog, attn);

    prep_points<<<NPTS_TOTAL / 256, 256, 0, stream>>>(refp, offlog, attn, idx_buf, w_buf);

    deform_sample<<<(BQ_TOTAL * N_HEADS) / 4, 256, 0, stream>>>(enc, idx_buf, w_buf, out);
}

// Round 5
// 215.954 us; speedup vs baseline: 1.0330x; 1.0330x over previous
//
#include <hip/hip_runtime.h>
#include <hip/hip_bf16.h>

// Problem constants (fixed by setup_inputs)
#define BQ_TOTAL 4800          // B*NQ = 16*300
#define D_MODEL 256
#define N_HEADS 8
#define SUM_POINTS 16
#define HEAD_DIM 32
#define SEQ 8500
#define OUT_ELEMS (BQ_TOTAL * D_MODEL)      // 1228800

typedef _Float16 half8 __attribute__((ext_vector_type(8)));
typedef _Float16 half4 __attribute__((ext_vector_type(4)));
typedef float floatx4 __attribute__((ext_vector_type(4)));

// ---------------- Kernel 1: logits GEMM via f16 MFMA ----------------
// C(4800 x 384) = hs(4800 x 256) @ [w_off; w_attn]^T + bias
// Tile 64x64, full K=256 staged to LDS as f16 once (single barrier).
// Wave w computes rows [w*16, w*16+16) x all 64 cols (4 col-tiles x 8 ksteps).
#define LDK 264   // 256 + 8 f16 pad -> 528 B row stride, 2-way-bank-free b128 reads

__global__ __launch_bounds__(256) void gemm_logits_mfma(
    const float* __restrict__ hs,
    const float* __restrict__ w_off, const float* __restrict__ b_off,
    const float* __restrict__ w_attn, const float* __restrict__ b_attn,
    float* __restrict__ off_out, float* __restrict__ attn_out)
{
    __shared__ _Float16 Asld[64 * LDK];
    __shared__ _Float16 Bsld[64 * LDK];

    const int tid = threadIdx.x;
    const int row0 = blockIdx.x * 64;       // query rows
    const int col0 = blockIdx.y * 64;       // output cols in [0,384)

    const float* Bsrc; const float* bias;
    if (col0 < 256) { Bsrc = w_off  + (size_t)col0 * 256;        bias = b_off  + col0; }
    else            { Bsrc = w_attn + (size_t)(col0 - 256) * 256; bias = b_attn + (col0 - 256); }

    // --- stage A and B tiles (64 x 256 each), fp32 -> f16 convert ---
    #pragma unroll
    for (int i = 0; i < 16; i++) {
        const int idx = tid + i * 256;      // 0..4095
        const int r = idx >> 6;             // 0..63
        const int kc = (idx & 63) << 2;     // 0..252, step 4

        const float4 a = *(const float4*)(hs + (size_t)(row0 + r) * 256 + kc);
        half4 ah; ah[0] = (_Float16)a.x; ah[1] = (_Float16)a.y;
                  ah[2] = (_Float16)a.z; ah[3] = (_Float16)a.w;
        *(half4*)&Asld[r * LDK + kc] = ah;

        const float4 b = *(const float4*)(Bsrc + (size_t)r * 256 + kc);
        half4 bh; bh[0] = (_Float16)b.x; bh[1] = (_Float16)b.y;
                  bh[2] = (_Float16)b.z; bh[3] = (_Float16)b.w;
        *(half4*)&Bsld[r * LDK + kc] = bh;
    }
    __syncthreads();

    // --- MFMA compute: A-frag m=lane&15 (row), k=quad*8+j; B-frag n=lane&15 (col) ---
    const int wv = tid >> 6;
    const int lane = tid & 63;
    const int m = lane & 15;
    const int quad = lane >> 4;

    half8 af[8];
    #pragma unroll
    for (int q8 = 0; q8 < 8; q8++)
        af[q8] = *(const half8*)&Asld[(wv * 16 + m) * LDK + q8 * 32 + quad * 8];

    floatx4 acc[4] = {{0.f,0.f,0.f,0.f},{0.f,0.f,0.f,0.f},{0.f,0.f,0.f,0.f},{0.f,0.f,0.f,0.f}};
    #pragma unroll
    for (int ct = 0; ct < 4; ct++) {
        #pragma unroll
        for (int q8 = 0; q8 < 8; q8++) {
            const half8 bf = *(const half8*)&Bsld[(ct * 16 + m) * LDK + q8 * 32 + quad * 8];
            acc[ct] = __builtin_amdgcn_mfma_f32_16x16x32_f16(af[q8], bf, acc[ct], 0, 0, 0);
        }
    }

    // --- epilogue: C/D layout col=lane&15, row=quad*4+reg; bias in fp32 ---
    #pragma unroll
    for (int ct = 0; ct < 4; ct++) {
        const int col_l = ct * 16 + m;        // 0..63 within tile
        const float bv = bias[col_l];
        #pragma unroll
        for (int rg = 0; rg < 4; rg++) {
            const int row = row0 + wv * 16 + quad * 4 + rg;
            const float v = acc[ct][rg] + bv;
            if (col0 < 256)
                off_out[(size_t)row * 256 + col0 + col_l] = v;
            else
                attn_out[(size_t)row * 128 + (col0 - 256) + col_l] = v;
        }
    }
}

// ---------------- Kernel 2: softmax + deformable sampling (v2 — best measured) ----------------
__global__ __launch_bounds__(256) void deform_sample(
    const float* __restrict__ enc,      // (16, 8500, 256)
    const float* __restrict__ refp,     // (4800, 4)
    const float* __restrict__ offlog,   // ws (4800, 256)
    float* __restrict__ attn,           // (4800, 128): logits in -> probs out
    float* __restrict__ out)            // (4800, 256)
{
    const int tid = threadIdx.x;
    const int w = tid >> 6;
    const int lane = tid & 63;
    const int item = blockIdx.x * 4 + w;   // 0..38399
    const int bq = item >> 3;              // b*300+q
    const int h = item & 7;
    const int p = lane >> 2;               // point 0..15
    const int sub = lane & 3;              // channel subgroup

    // --- softmax over 16 points, wave-wide (xor strides 4..32 permute p) ---
    float* attn_ptr = attn + (size_t)bq * 128 + h * 16;
    const float l = attn_ptr[p];
    float m = l;
    #pragma unroll
    for (int s = 4; s < 64; s <<= 1) m = fmaxf(m, __shfl_xor(m, s));
    const float e = __expf(l - m);
    float ssum = e;
    #pragma unroll
    for (int s = 4; s < 64; s <<= 1) ssum += __shfl_xor(ssum, s);
    const float prob = e / ssum;
    if (sub == 0) attn_ptr[p] = prob;      // second output

    // --- per-point sampling location ---
    const float2 off2 = *(const float2*)(offlog + (size_t)bq * 256 + h * 32 + 2 * p);
    const float* rp = refp + (size_t)bq * 4;
    const float cx = rp[0], cy = rp[1], rw = rp[2], rh = rp[3];

    const int lvl = p >> 2;
    const int Wl = 80 >> lvl;              // square levels
    int base = 0;
    if (lvl == 1) base = 6400;
    else if (lvl == 2) base = 8000;
    else if (lvl == 3) base = 8400;

    const float Wf = (float)Wl;
    // offset = logit * (1/P=0.25) * ref_wh * OFFSET_SCALE(0.5) = logit * 0.125 * wh
    const float gx = (cx + off2.x * 0.125f * rw) * Wf - 0.5f;
    const float gy = (cy + off2.y * 0.125f * rh) * Wf - 0.5f;
    const float x0f = floorf(gx), y0f = floorf(gy);
    const float fx = gx - x0f, fy = gy - y0f;
    const int x0 = (int)x0f, y0 = (int)y0f;

    const int b = bq / 300;
    const float* pbase = enc + ((size_t)b * SEQ + base) * 256 + h * 32 + sub * 4;

    float4 acc0 = {0.f, 0.f, 0.f, 0.f};
    float4 acc1 = {0.f, 0.f, 0.f, 0.f};
    #pragma unroll
    for (int c = 0; c < 4; c++) {
        const int xc = x0 + (c & 1);
        const int yc = y0 + (c >> 1);
        const float wx = (c & 1) ? fx : (1.0f - fx);
        const float wy = (c >> 1) ? fy : (1.0f - fy);
        const bool valid = (xc >= 0) && (xc < Wl) && (yc >= 0) && (yc < Wl);
        const int xi = min(max(xc, 0), Wl - 1);
        const int yi = min(max(yc, 0), Wl - 1);
        const float wgt = valid ? wx * wy : 0.0f;
        const float* vp = pbase + (size_t)(yi * Wl + xi) * 256;
        const float4 va = *(const float4*)(vp);
        const float4 vb = *(const float4*)(vp + 16);
        acc0.x += wgt * va.x; acc0.y += wgt * va.y;
        acc0.z += wgt * va.z; acc0.w += wgt * va.w;
        acc1.x += wgt * vb.x; acc1.y += wgt * vb.y;
        acc1.z += wgt * vb.z; acc1.w += wgt * vb.w;
    }

    float vals[8];
    vals[0] = acc0.x * prob; vals[1] = acc0.y * prob;
    vals[2] = acc0.z * prob; vals[3] = acc0.w * prob;
    vals[4] = acc1.x * prob; vals[5] = acc1.y * prob;
    vals[6] = acc1.z * prob; vals[7] = acc1.w * prob;

    // reduce over points (lanes differing in bits 2..5)
    #pragma unroll
    for (int s = 4; s < 64; s <<= 1) {
        #pragma unroll
        for (int j = 0; j < 8; j++) vals[j] += __shfl_xor(vals[j], s);
    }

    if (lane < 8) {
        const int halfs = lane >> 2;       // 0: chans [0,16), 1: [16,32)
        const int sb = lane & 3;
        float4 v;
        if (halfs == 0) { v.x = vals[0]; v.y = vals[1]; v.z = vals[2]; v.w = vals[3]; }
        else            { v.x = vals[4]; v.y = vals[5]; v.z = vals[6]; v.w = vals[7]; }
        out[(size_t)bq * 256 + h * 32 + halfs * 16 + sb * 4 + 0] = v.x;
        out[(size_t)bq * 256 + h * 32 + halfs * 16 + sb * 4 + 1] = v.y;
        out[(size_t)bq * 256 + h * 32 + halfs * 16 + sb * 4 + 2] = v.z;
        out[(size_t)bq * 256 + h * 32 + halfs * 16 + sb * 4 + 3] = v.w;
    }
}

extern "C" void kernel_launch(void* const* d_in, const int* in_sizes, int n_in,
                              void* d_out, int out_size, void* d_ws, size_t ws_size,
                              hipStream_t stream) {
    const float* hs     = (const float*)d_in[0];   // (16,300,256)
    const float* enc    = (const float*)d_in[1];   // (16,8500,256)
    const float* refp   = (const float*)d_in[2];   // (16,300,1,4)
    // d_in[3] = spatial_shapes (int64) — static, hardcoded
    const float* w_off  = (const float*)d_in[4];   // (256,256)
    const float* b_off  = (const float*)d_in[5];   // (256,)
    const float* w_attn = (const float*)d_in[6];   // (128,256)
    const float* b_attn = (const float*)d_in[7];   // (128,)

    float* out  = (float*)d_out;            // (16,300,256)
    float* attn = out + OUT_ELEMS;          // (16,300,8,16)
    float* offlog = (float*)d_ws;           // (4800,256) fp32 = 4.9 MB

    dim3 g1(BQ_TOTAL / 64, 384 / 64);       // (75, 6)
    gemm_logits_mfma<<<g1, 256, 0, stream>>>(hs, w_off, b_off, w_attn, b_attn, offlog, attn);

    deform_sample<<<(BQ_TOTAL * N_HEADS) / 4, 256, 0, stream>>>(enc, refp, offlog, attn, out);
}